// Round 6
// baseline (1752.044 us; speedup 1.0000x reference)
//
#include <hip/hip_runtime.h>
#include <cmath>
#include <cstdint>

typedef __bf16 bf16x8 __attribute__((ext_vector_type(8)));
typedef float  f32x4  __attribute__((ext_vector_type(4)));
typedef float  f32x16 __attribute__((ext_vector_type(16)));

#define EPSF 1e-5f
// B=32, total in-ch=65, H=32, W=16 -> 512 pixels. cpt: (32,64,32,16) fp32.
// GEMM: z2[32,4096] = a[32,32768] @ plus_w[4096,32768]^T, 4 iterations.
// plus_w fp32 (512 MiB) -> bf16 K-interleaved MFMA-fragment tiling (256 MiB ws),
// built once per call. GEMM: 32 K-splits x 128 n-tiles = 4096 waves, NO atomics —
// each wave plain-stores its 16 partials into z2p[32][32][4096] (each cell written
// exactly once); prep2 folds the 32-way reduction + plus_b bias. The 2M device-scope
// atomicAdds/GEMM of R0-R4 (16-way address collision) are the suspected hidden cost.

#define NSPLIT 32          // K-splits
#define KSTEPS 64          // K16 steps per split (NSPLIT*KSTEPS = 2048)

// ---------------- head: convc/convp/convt + time MLP + poi + bn1(relu) + conv1 ----------------
__global__ __launch_bounds__(64) void head_kernel(
    const float* __restrict__ x,
    const float* __restrict__ cw, const float* __restrict__ cb,
    const float* __restrict__ pw, const float* __restrict__ pb,
    const float* __restrict__ tw, const float* __restrict__ tb,
    const float* __restrict__ tmw, const float* __restrict__ tmb,
    const float* __restrict__ tfw, const float* __restrict__ tfb,
    const float* __restrict__ poiw, const float* __restrict__ poib,
    const float* __restrict__ g1, const float* __restrict__ bb1,
    const float* __restrict__ m1, const float* __restrict__ v1,
    const float* __restrict__ w1, const float* __restrict__ b1c,
    float* __restrict__ cpt)
{
    int pix = blockIdx.x;            // 0..16383
    int b = pix >> 9, p = pix & 511;
    int t = threadIdx.x;             // 0..63

    __shared__ float xs[65];
    __shared__ float tx1[28];
    __shared__ float y[201];
    __shared__ float tx2s;

    for (int c = t; c < 65; c += 64)
        xs[c] = x[(b * 65 + c) * 512 + p];
    __syncthreads();

    if (t < 28) {
        float acc = tmb[t];
        for (int j = 0; j < 31; ++j) acc += tmw[t * 31 + j] * xs[34 + j];
        tx1[t] = fmaxf(acc, 0.f);
    }
    __syncthreads();
    if (t == 0) {
        float acc = tfb[0];
        for (int j = 0; j < 28; ++j) acc += tfw[j] * tx1[j];
        tx2s = fmaxf(acc, 0.f);
    }
    __syncthreads();
    float tx2 = tx2s;

    { // closeness: out ch 0..63, K=6 (x ch 0..5)
        float acc = cb[t];
        for (int j = 0; j < 6; ++j) acc += cw[t * 6 + j] * xs[j];
        y[t] = acc;
    }
    { // period: out ch 64..127, K=8 (x ch 6..13)
        float acc = pb[t];
        for (int j = 0; j < 8; ++j) acc += pw[t * 8 + j] * xs[6 + j];
        y[64 + t] = acc;
    }
    { // trend: out ch 128..191, K=8 (x ch 14..21)
        float acc = tb[t];
        for (int j = 0; j < 8; ++j) acc += tw[t * 8 + j] * xs[14 + j];
        y[128 + t] = acc;
    }
    if (t < 9) { // poi_time: out ch 192..200 (poi = x ch 22..33)
        float acc = poib[t];
        for (int j = 0; j < 12; ++j) acc += poiw[t * 12 + j] * (tx2 * xs[22 + j]);
        y[192 + t] = acc;
    }
    // bn1(relu(.)) applied by the same thread that wrote each channel
    for (int c = t; c < 201; c += 64) {
        float s  = g1[c] * rsqrtf(v1[c] + EPSF);
        float tt = bb1[c] - m1[c] * s;
        y[c] = fmaxf(y[c], 0.f) * s + tt;
    }
    __syncthreads();

    float acc = b1c[t];
    const float* wrow = w1 + t * 201;
    for (int c = 0; c < 201; ++c) acc += wrow[c] * y[c];
    cpt[(b * 64 + t) * 512 + p] = acc;
}

// ---------------- wconv_tiled: plus_w fp32 -> bf16 K-interleaved MFMA fragments ----------------
// Fragment(nt, k16), element (l, e) = W[nt*32 + (l&31)][k16*16 + (l>>5)*8 + e],
// stored at wt[ ((it*NSPLIT + ks)*128 + nt)*512 + l*8 + e ], it = k16 & 63, ks = k16 >> 6.
// At GEMM step `it`, all 4096 waves read one dense 4 MiB window.
__global__ __launch_bounds__(256) void wconv_tiled_kernel(const float* __restrict__ w,
                                                          __bf16* __restrict__ wt)
{
    __shared__ __bf16 lds[32 * 528];   // 32 local-k16 groups x (512 data + 16 pad)
    int nt = blockIdx.x;               // 0..127
    int kg = blockIdx.y;               // 0..63
    int t  = threadIdx.x;              // 0..255

    // phase 1: read rows coalesced (8 B/lane), convert, scatter to LDS tiled order
    int klo  = t * 2;                  // local k, 0..510
    int g16l = klo >> 4;
    int hi   = (klo >> 3) & 1;
    int e    = klo & 7;                // even
    __bf16* d = &lds[g16l * 528 + hi * 256 + e];
    const float* src0 = w + (long)(nt * 32) * 32768 + kg * 512 + klo;
    for (int r = 0; r < 32; ++r) {
        float2 v = *(const float2*)(src0 + (long)r * 32768);
        d[r * 8 + 0] = (__bf16)v.x;
        d[r * 8 + 1] = (__bf16)v.y;
    }
    __syncthreads();

    // phase 2: write 2048 x 16B fragment pieces; each wave writes one contiguous 1 KiB
#pragma unroll
    for (int j = 0; j < 8; ++j) {
        int fid = j * 256 + t;         // 0..2047 = gl*64 + l
        int gl = fid >> 6;             // local k16 index 0..31
        int l  = fid & 63;
        int k16 = kg * 32 + gl;        // global k16, 0..2047
        int it  = k16 & (KSTEPS - 1);
        int ks  = k16 >> 6;            // k16 / KSTEPS
        bf16x8 v = *(const bf16x8*)&lds[gl * 528 + (l >> 5) * 256 + (l & 31) * 8];
        long off = ((long)(it * NSPLIT + ks) * 128 + nt) * 512 + l * 8;
        *(bf16x8*)(wt + off) = v;
    }
}

// ---------------- prep_tiled: a_t = bn1(relu(cpt)) as bf16, k-major fragment layout ----------
// a_t element (k16*64 + hi*32 + b)*8 + e = A[b][k], k = k16*16 + hi*8 + e, k = c*512 + p.
__global__ void prep_tiled_kernel(const float* __restrict__ cpt,
                                  const float* __restrict__ g, const float* __restrict__ bb,
                                  const float* __restrict__ m, const float* __restrict__ v,
                                  __bf16* __restrict__ a_t)
{
    int i = blockIdx.x * blockDim.x + threadIdx.x;
    if (i >= 32 * 64 * 512) return;
    int b = i >> 15, c = (i >> 9) & 63, p = i & 511;
    float s  = g[c] * rsqrtf(v[c] + EPSF);
    float tt = bb[c] - m[c] * s;
    float val = fmaxf(cpt[i], 0.f) * s + tt;
    int k = c * 512 + p;
    int idx = ((k >> 4) * 64 + ((k >> 3) & 1) * 32 + b) * 8 + (k & 7);
    a_t[idx] = (__bf16)val;
}

// ---------------- prep (fallback, linear A layout) ----------------
__global__ void prep_kernel(const float* __restrict__ cpt,
                            const float* __restrict__ g, const float* __restrict__ bb,
                            const float* __restrict__ m, const float* __restrict__ v,
                            __bf16* __restrict__ a_bf)
{
    int i = blockIdx.x * blockDim.x + threadIdx.x;
    if (i >= 32 * 64 * 512) return;
    int c = (i >> 9) & 63;
    float s  = g[c] * rsqrtf(v[c] + EPSF);
    float tt = bb[c] - m[c] * s;
    a_bf[i] = (__bf16)(fmaxf(cpt[i], 0.f) * s + tt);
}

// ---------------- GEMM (fallback, fp32 W stream, plain-store partials) ----------------
__global__ __launch_bounds__(256) void gemm_kernel(const __bf16* __restrict__ a_bf,
                                                   const float* __restrict__ plus_w,
                                                   float* __restrict__ z2p)
{
    int wave = threadIdx.x >> 6;
    int lane = threadIdx.x & 63;
    int gw = blockIdx.x * 4 + wave;   // 0..4095
    int nt = gw & 127;                // 128 n-tiles of 32
    int ks = gw >> 7;                 // 32 K-splits of 1024
    int r32 = lane & 31;
    int hi  = lane >> 5;
    int n = nt * 32 + r32;
    long k0 = (long)ks * 1024 + hi * 8;

    const float*  wp = plus_w + (long)n * 32768 + k0;
    const bf16x8* ap = (const bf16x8*)(a_bf + (long)r32 * 32768 + k0);

    f32x16 acc = {};
#pragma unroll 4
    for (int it = 0; it < KSTEPS; ++it) {       // 64 * K16 = 1024
        f32x4 w0 = *(const f32x4*)(wp + it * 16);
        f32x4 w1 = *(const f32x4*)(wp + it * 16 + 4);
        bf16x8 bfr;
#pragma unroll
        for (int j = 0; j < 4; ++j) { bfr[j] = (__bf16)w0[j]; bfr[j + 4] = (__bf16)w1[j]; }
        bf16x8 afr = ap[it * 2];
        acc = __builtin_amdgcn_mfma_f32_32x32x16_bf16(afr, bfr, acc, 0, 0, 0);
    }
#pragma unroll
    for (int r = 0; r < 16; ++r) {
        int brow = (r & 3) + 8 * (r >> 2) + 4 * hi;
        z2p[((ks * 32 + brow) * 4096) + n] = acc[r];
    }
}

// ---------------- GEMM (K-interleaved bf16 fragments, register loads, NO atomics) -------------
// 1024 blocks x 4 waves = 4096 waves; wave = (ks, nt), ks in [0,32), nt in [0,128).
// Step it: W fragment at ((it*32+ks)*128 + nt)*512 + lane*8 — all waves share one dense
// 4 MiB window per step. A fragment at (ks*64+it)*512 + lane*8 (2 MiB, L2/L3-hot).
// Epilogue: 16 plain stores per lane into z2p[(ks*32+brow)*4096+n] — written exactly once.
__global__ __launch_bounds__(256, 4) void gemm_reg_kernel(const __bf16* __restrict__ a_t,
                                                          const __bf16* __restrict__ w_t,
                                                          float* __restrict__ z2p)
{
    int wave = threadIdx.x >> 6;
    int lane = threadIdx.x & 63;
    int gw = blockIdx.x * 4 + wave;   // 0..4095
    int nt = gw & 127;                // n-tile of 32 cols
    int ks = gw >> 7;                 // K-split, 0..31
    int r32 = lane & 31;
    int hi  = lane >> 5;
    int n = nt * 32 + r32;

    // bf16x8-unit pointers (one fragment = 64 units of 16 B; lane owns unit `lane`)
    const bf16x8* ap = (const bf16x8*)a_t + (long)ks * KSTEPS * 64 + lane;
    const bf16x8* wp = (const bf16x8*)w_t + ((long)ks * 128 + nt) * 64 + lane;

    f32x16 acc = {};
#pragma unroll 4
    for (int it = 0; it < KSTEPS; ++it) {
        bf16x8 afr = ap[(long)it * 64];        // +1 KiB per step (contiguous per wave)
        bf16x8 bfr = wp[(long)it * 262144];    // +4 MiB per step (dense across waves)
        acc = __builtin_amdgcn_mfma_f32_32x32x16_bf16(afr, bfr, acc, 0, 0, 0);
    }

    // C/D layout (m74/m101): col(n)=lane&31, row(b)=(reg&3)+8*(reg>>2)+4*(lane>>5)
#pragma unroll
    for (int r = 0; r < 16; ++r) {
        int brow = (r & 3) + 8 * (r >> 2) + 4 * hi;
        z2p[((ks * 32 + brow) * 4096) + n] = acc[r];
    }
}

// ---------------- conv3x3 #1: z1 = conv(relu(bn1(cpt)), rp_conv1_w) + b, 56 out ch ----------------
__global__ __launch_bounds__(512) void conv1_kernel(const float* __restrict__ cpt,
                                                    const float* __restrict__ g, const float* __restrict__ bb,
                                                    const float* __restrict__ m, const float* __restrict__ v,
                                                    const float* __restrict__ w,
                                                    const float* __restrict__ bias,
                                                    float* __restrict__ z1)
{
    int b  = blockIdx.x;        // 0..31
    int og = blockIdx.y;        // 0..13 (4 out-ch each)
    int p  = threadIdx.x;       // 0..511
    int h = p >> 4, wc = p & 15;
    int o0 = og * 4;

    __shared__ float ss[64], ts[64];
    if (p < 64) {
        float s = g[p] * rsqrtf(v[p] + EPSF);
        ss[p] = s;
        ts[p] = bb[p] - m[p] * s;
    }
    __syncthreads();

    float a0 = bias[o0], a1 = bias[o0 + 1], a2 = bias[o0 + 2], a3 = bias[o0 + 3];
    const float* rb = cpt + b * 64 * 512;
    for (int c = 0; c < 64; ++c) {
        const float* rc = rb + c * 512;
        float s = ss[c], tt = ts[c];
        float rv[9];
#pragma unroll
        for (int dh = -1; dh <= 1; ++dh)
#pragma unroll
            for (int dw = -1; dw <= 1; ++dw) {
                int hh = h + dh, ww = wc + dw;
                bool ok = (hh >= 0) & (hh < 32) & (ww >= 0) & (ww < 16);
                rv[(dh + 1) * 3 + (dw + 1)] = ok ? fmaxf(rc[hh * 16 + ww] * s + tt, 0.f) : 0.f;
            }
#pragma unroll
        for (int tp = 0; tp < 9; ++tp) {
            a0 += rv[tp] * w[((o0    ) * 64 + c) * 9 + tp];
            a1 += rv[tp] * w[((o0 + 1) * 64 + c) * 9 + tp];
            a2 += rv[tp] * w[((o0 + 2) * 64 + c) * 9 + tp];
            a3 += rv[tp] * w[((o0 + 3) * 64 + c) * 9 + tp];
        }
    }
    float* zb = z1 + ((b * 56 + o0) * 512) + p;
    zb[0] = a0; zb[512] = a1; zb[1024] = a2; zb[1536] = a3;
}

// ---------------- prep2: z3 = relu(bn2(concat(z1, reduce(z2p)+bias))) -> bf16 ----------------
__global__ void prep2_kernel(const float* __restrict__ z1, const float* __restrict__ z2p,
                             const float* __restrict__ plus_b,
                             const float* __restrict__ g, const float* __restrict__ bb,
                             const float* __restrict__ m, const float* __restrict__ v,
                             __bf16* __restrict__ z3)
{
    int i = blockIdx.x * blockDim.x + threadIdx.x;
    if (i >= 32 * 64 * 512) return;
    int b = i >> 15, c = (i >> 9) & 63, p = i & 511;
    float val;
    if (c < 56) {
        val = z1[(b * 56 + c) * 512 + p];
    } else {
        int n = (c - 56) * 512 + p;
        val = plus_b[n];
        const float* zp = z2p + b * 4096 + n;
#pragma unroll
        for (int ks = 0; ks < NSPLIT; ++ks)
            val += zp[(long)ks * 32 * 4096];
    }
    float s  = g[c] * rsqrtf(v[c] + EPSF);
    float tt = bb[c] - m[c] * s;
    z3[i] = (__bf16)fmaxf(val * s + tt, 0.f);
}

// ---------------- conv3x3 #2: cpt += conv(z3, rp_conv2_w) + b (in-place residual) -----------
__global__ __launch_bounds__(512) void conv2_kernel(const __bf16* __restrict__ z3,
                                                    const float* __restrict__ w,
                                                    const float* __restrict__ bias,
                                                    float* __restrict__ cpt)
{
    int b  = blockIdx.x;        // 0..31
    int og = blockIdx.y;        // 0..15
    int p  = threadIdx.x;       // 0..511
    int h = p >> 4, wc = p & 15;
    int o0 = og * 4;
    float a0 = bias[o0], a1 = bias[o0 + 1], a2 = bias[o0 + 2], a3 = bias[o0 + 3];
    const __bf16* rb = z3 + b * 64 * 512;
    for (int c = 0; c < 64; ++c) {
        const __bf16* rc = rb + c * 512;
        float rv[9];
#pragma unroll
        for (int dh = -1; dh <= 1; ++dh)
#pragma unroll
            for (int dw = -1; dw <= 1; ++dw) {
                int hh = h + dh, ww = wc + dw;
                bool ok = (hh >= 0) & (hh < 32) & (ww >= 0) & (ww < 16);
                rv[(dh + 1) * 3 + (dw + 1)] = ok ? (float)rc[hh * 16 + ww] : 0.f;
            }
#pragma unroll
        for (int tp = 0; tp < 9; ++tp) {
            a0 += rv[tp] * w[((o0    ) * 64 + c) * 9 + tp];
            a1 += rv[tp] * w[((o0 + 1) * 64 + c) * 9 + tp];
            a2 += rv[tp] * w[((o0 + 2) * 64 + c) * 9 + tp];
            a3 += rv[tp] * w[((o0 + 3) * 64 + c) * 9 + tp];
        }
    }
    float* cb_ = cpt + ((b * 64 + o0) * 512) + p;
    cb_[0]    += a0;
    cb_[512]  += a1;
    cb_[1024] += a2;
    cb_[1536] += a3;
}

// ---------------- tail: out = tanh(conv2(bn2(relu(cpt)))) -> fp32 ----------------
__global__ void tail_kernel(const float* __restrict__ cpt,
                            const float* __restrict__ g, const float* __restrict__ bb,
                            const float* __restrict__ m, const float* __restrict__ v,
                            const float* __restrict__ w2, const float* __restrict__ b2,
                            float* __restrict__ out)
{
    int i = blockIdx.x * blockDim.x + threadIdx.x;
    if (i >= 32 * 512) return;
    int b = i >> 9, p = i & 511;
    float a0 = b2[0], a1 = b2[1];
    for (int c = 0; c < 64; ++c) {
        float s  = g[c] * rsqrtf(v[c] + EPSF);
        float tt = bb[c] - m[c] * s;
        float y = fmaxf(cpt[(b * 64 + c) * 512 + p], 0.f) * s + tt;
        a0 += w2[c] * y;
        a1 += w2[64 + c] * y;
    }
    out[(b * 2 + 0) * 512 + p] = tanhf(a0);
    out[(b * 2 + 1) * 512 + p] = tanhf(a1);
}

extern "C" void kernel_launch(void* const* d_in, const int* in_sizes, int n_in,
                              void* d_out, int out_size, void* d_ws, size_t ws_size,
                              hipStream_t stream)
{
#define IN(i) ((const float*)d_in[i])
    // workspace layout:
    //   [0,      4 MiB) cpt   : 32*64*512 fp32
    //   [4 MiB,  6 MiB) a_t   : 32*64*512 bf16 fragment-tiled GEMM A — ALIASED with z3
    //                           (safe: a_t consumed by gemm before prep2 writes z3;
    //                            z3 consumed by conv2 before next prep rewrites a_t)
    //   [6 MiB,  9.5MiB) z1   : 32*56*512 fp32
    //   [10 MiB, 26 MiB) z2p  : 32 K-split partials x 32 b x 4096 n fp32 (16 MiB),
    //                           fully overwritten by every gemm dispatch (no init)
    //   [32 MiB, 288 MiB) w_t : 4096*32768 bf16 K-interleaved fragment-tiled plus_w,
    //                           rebuilt every call by wconv_tiled (re-poisoning harmless)
    float*  cpt  = (float*)d_ws;
    __bf16* a_t  = (__bf16*)((char*)d_ws + (size_t)4 * 1024 * 1024);
    __bf16* z3   = a_t;
    float*  z1   = (float*)((char*)d_ws + (size_t)6 * 1024 * 1024);
    float*  z2p  = (float*)((char*)d_ws + (size_t)10 * 1024 * 1024);
    __bf16* w_t  = (__bf16*)((char*)d_ws + (size_t)32 * 1024 * 1024);

    const bool cacheW = ws_size >= (size_t)288 * 1024 * 1024;

    if (cacheW)
        wconv_tiled_kernel<<<dim3(128, 64), 256, 0, stream>>>(IN(31), w_t);

    head_kernel<<<16384, 64, 0, stream>>>(
        IN(0), IN(1), IN(2), IN(3), IN(4), IN(5), IN(6), IN(7), IN(8), IN(9), IN(10),
        IN(11), IN(12), IN(13), IN(14), IN(15), IN(16), IN(17), IN(18), cpt);

    for (int it = 0; it < 4; ++it) {
        if (cacheW) {
            prep_tiled_kernel<<<4096, 256, 0, stream>>>(cpt, IN(19), IN(20), IN(21), IN(22), a_t);
            gemm_reg_kernel<<<1024, 256, 0, stream>>>(a_t, w_t, z2p);
        } else {
            prep_kernel<<<4096, 256, 0, stream>>>(cpt, IN(19), IN(20), IN(21), IN(22), a_t);
            gemm_kernel<<<1024, 256, 0, stream>>>(a_t, IN(31), z2p);
        }
        conv1_kernel<<<dim3(32, 14), 512, 0, stream>>>(cpt, IN(19), IN(20), IN(21), IN(22),
                                                       IN(23), IN(24), z1);
        prep2_kernel<<<4096, 256, 0, stream>>>(z1, z2p, IN(32), IN(25), IN(26), IN(27), IN(28), z3);
        conv2_kernel<<<dim3(32, 16), 512, 0, stream>>>(z3, IN(29), IN(30), cpt);
    }

    tail_kernel<<<64, 256, 0, stream>>>(cpt, IN(33), IN(34), IN(35), IN(36),
                                        IN(37), IN(38), (float*)d_out);
#undef IN
}